// Round 2
// baseline (9764.011 us; speedup 1.0000x reference)
//
#include <hip/hip_runtime.h>
#include <math.h>

#define BB 8
#define NN 512
#define DD 512
#define HH 8
#define DHH 64
#define FFF 2048
#define MEMM 4096
#define TOPKK 32
#define DEPTHH 6
#define NT (BB*NN)   /* 4096 tokens */

// ---------------- LayerNorm ----------------
__global__ __launch_bounds__(256) void ln_kernel(const float* __restrict__ xin,
                                                 const float* __restrict__ g,
                                                 const float* __restrict__ bt,
                                                 float* __restrict__ out) {
  __shared__ float red[4];
  int tok = blockIdx.x;
  const float* xr = xin + (size_t)tok * DD;
  int t = threadIdx.x;
  float v0 = xr[t], v1 = xr[t + 256];
  float s = v0 + v1;
#pragma unroll
  for (int m = 32; m; m >>= 1) s += __shfl_xor(s, m, 64);
  if ((t & 63) == 0) red[t >> 6] = s;
  __syncthreads();
  float mean = (red[0] + red[1] + red[2] + red[3]) * (1.0f / 512.0f);
  float d0 = v0 - mean, d1 = v1 - mean;
  float vv = d0 * d0 + d1 * d1;
#pragma unroll
  for (int m = 32; m; m >>= 1) vv += __shfl_xor(vv, m, 64);
  __syncthreads();
  if ((t & 63) == 0) red[t >> 6] = vv;
  __syncthreads();
  float var = (red[0] + red[1] + red[2] + red[3]) * (1.0f / 512.0f);
  float inv = rsqrtf(var + 1e-5f);
  out[(size_t)tok * DD + t]       = d0 * inv * g[t] + bt[t];
  out[(size_t)tok * DD + t + 256] = d1 * inv * g[t + 256] + bt[t + 256];
}

__device__ inline float gelu_f(float x) {
  float x3 = x * x * x;
  return 0.5f * x * (1.0f + tanhf(0.7978845608028654f * (x + 0.044715f * x3)));
}

// ---------------- SGEMM: C = A(MxK) @ B(KxN) [EPI: 0 none, 1 gelu, 2 +R] ----
template <int EPI>
__global__ __launch_bounds__(256) void gemm_kernel(const float* __restrict__ A,
                                                   const float* __restrict__ Bm,
                                                   const float* __restrict__ R,
                                                   float* __restrict__ C,
                                                   int M, int Nc, int K) {
  __shared__ float As[16][68];
  __shared__ float Bs[16][68];
  int tx = threadIdx.x & 15, ty = threadIdx.x >> 4;
  int bm = blockIdx.y, bn = blockIdx.x;
  int r0 = ty * 4, c0 = tx * 4;
  float acc[4][4] = {};
  for (int kt = 0; kt < K; kt += 16) {
    {  // A tile 64x16 -> As[k][row] (transposed)
      int row = threadIdx.x >> 2;
      int kk = (threadIdx.x & 3) * 4;
      float4 a4 = *(const float4*)(A + (size_t)(bm * 64 + row) * K + kt + kk);
      As[kk + 0][row] = a4.x; As[kk + 1][row] = a4.y;
      As[kk + 2][row] = a4.z; As[kk + 3][row] = a4.w;
    }
    {  // B tile 16x64 -> Bs[k][col]
      int kk = threadIdx.x >> 4;
      int col = (threadIdx.x & 15) * 4;
      *(float4*)&Bs[kk][col] = *(const float4*)(Bm + (size_t)(kt + kk) * Nc + bn * 64 + col);
    }
    __syncthreads();
#pragma unroll
    for (int kk = 0; kk < 16; kk++) {
      float4 a4 = *(const float4*)&As[kk][r0];
      float4 b4 = *(const float4*)&Bs[kk][c0];
      float a_[4] = {a4.x, a4.y, a4.z, a4.w};
      float b_[4] = {b4.x, b4.y, b4.z, b4.w};
#pragma unroll
      for (int i = 0; i < 4; i++)
#pragma unroll
        for (int j = 0; j < 4; j++) acc[i][j] += a_[i] * b_[j];
    }
    __syncthreads();
  }
#pragma unroll
  for (int i = 0; i < 4; i++) {
    size_t off = (size_t)(bm * 64 + r0 + i) * Nc + bn * 64 + c0;
    float4 o;
    if (EPI == 1) {
      o.x = gelu_f(acc[i][0]); o.y = gelu_f(acc[i][1]);
      o.z = gelu_f(acc[i][2]); o.w = gelu_f(acc[i][3]);
    } else if (EPI == 2) {
      float4 rv = *(const float4*)(R + off);
      o.x = rv.x + acc[i][0]; o.y = rv.y + acc[i][1];
      o.z = rv.z + acc[i][2]; o.w = rv.w + acc[i][3];
    } else {
      o.x = acc[i][0]; o.y = acc[i][1]; o.z = acc[i][2]; o.w = acc[i][3];
    }
    *(float4*)(C + off) = o;
  }
}

// ---------------- fused q@mem_k + running top-32 ----------------
// grid (N/32, H, B), block 256. topv/topi layout [((b*H+h)*N + i)][TOPK]
__global__ __launch_bounds__(256) void knn_topk_kernel(const float* __restrict__ q,
                                                       const float* __restrict__ mem_k,
                                                       float* __restrict__ topv,
                                                       int* __restrict__ topi) {
  int it = blockIdx.x, h = blockIdx.y, b = blockIdx.z;
  __shared__ float qs[32][68];
  __shared__ float ks[64][68];
  __shared__ float sc[32][68];
  __shared__ float tv[32][TOPKK];
  __shared__ int ti[32][TOPKK];
  const float scale = 0.125f;
  int t = threadIdx.x;
  {  // load 32 q rows
    int row = t >> 3;
    int col = (t & 7) * 8;
    const float* qp = q + ((size_t)(b * NN + it * 32 + row)) * DD + h * DHH + col;
    *(float4*)&qs[row][col]     = *(const float4*)qp;
    *(float4*)&qs[row][col + 4] = *(const float4*)(qp + 4);
  }
  if (t < 32) {
#pragma unroll
    for (int k2 = 0; k2 < TOPKK; k2++) { tv[t][k2] = -INFINITY; ti[t][k2] = 0; }
  }
  float thr = -INFINITY;  // running min of top-32 (valid for t<32)
  __syncthreads();
  for (int mt = 0; mt < MEMM; mt += 64) {
#pragma unroll
    for (int i = 0; i < 4; i++) {  // load mem_k tile 64x64
      int lin = i * 256 + t;
      int row = lin >> 4, col = (lin & 15) * 4;
      *(float4*)&ks[row][col] =
          *(const float4*)(mem_k + ((size_t)b * MEMM + mt + row) * DHH + col);
    }
    __syncthreads();
    {  // scores: r = t&31, 8 cols
      int r = t & 31, cg = t >> 5;
      float s[8] = {};
#pragma unroll
      for (int d4 = 0; d4 < 64; d4 += 4) {
        float4 q4 = *(const float4*)&qs[r][d4];
#pragma unroll
        for (int j = 0; j < 8; j++) {
          float4 k4 = *(const float4*)&ks[cg * 8 + j][d4];
          s[j] += q4.x * k4.x + q4.y * k4.y + q4.z * k4.z + q4.w * k4.w;
        }
      }
#pragma unroll
      for (int j = 0; j < 8; j++) sc[r][cg * 8 + j] = s[j] * scale;
    }
    __syncthreads();
    if (t < 32) {  // serial replace-min top-32 per row
      int rr = t;
      for (int c = 0; c < 64; c++) {
        float sv = sc[rr][c];
        if (sv > thr) {
          int mi2 = 0; float mv = tv[rr][0];
#pragma unroll
          for (int k2 = 1; k2 < TOPKK; k2++) {
            float tvv = tv[rr][k2];
            if (tvv < mv) { mv = tvv; mi2 = k2; }
          }
          tv[rr][mi2] = sv; ti[rr][mi2] = mt + c;
          mv = tv[rr][0];
#pragma unroll
          for (int k2 = 1; k2 < TOPKK; k2++) mv = fminf(mv, tv[rr][k2]);
          thr = mv;
        }
      }
    }
    __syncthreads();
  }
  if (t < 32) {
    size_t rowg = ((size_t)b * HH + h) * NN + it * 32 + t;
#pragma unroll
    for (int k2 = 0; k2 < TOPKK; k2++) {
      topv[rowg * TOPKK + k2] = tv[t][k2];
      topi[rowg * TOPKK + k2] = ti[t][k2];
    }
  }
}

// ---------------- flash attention (+ optional kNN memory logits) ----------
// grid (N/64, H, B), block 256. ao layout [b][i][h*64+d]
__global__ __launch_bounds__(256) void attn_kernel(const float* __restrict__ q,
                                                   const float* __restrict__ k,
                                                   const float* __restrict__ v,
                                                   float* __restrict__ ao,
                                                   const float* __restrict__ topv,
                                                   const int* __restrict__ topi,
                                                   const float* __restrict__ mem_v,
                                                   int knn) {
  int bi = blockIdx.x, h = blockIdx.y, b = blockIdx.z;
  __shared__ float ks[64][64];
  __shared__ float vs[64][64];
  __shared__ float sc[64][65];
  __shared__ float marr[64], larr[64], aarr[64];
  __shared__ int pidx[64][33];
  const float scale = 0.125f;
  int t = threadIdx.x;
  int r = t & 63;   // row role
  int w = t >> 6;   // wave: phase1 col-group / phase2 d-group
  int i0 = bi * 64;
  int iglob = i0 + r;

  float qreg[64];
  {
    const float* qp = q + ((size_t)(b * NN) + iglob) * DD + h * DHH;
#pragma unroll
    for (int d4 = 0; d4 < 64; d4 += 4) {
      float4 a = *(const float4*)(qp + d4);
      qreg[d4] = a.x * scale; qreg[d4 + 1] = a.y * scale;
      qreg[d4 + 2] = a.z * scale; qreg[d4 + 3] = a.w * scale;
    }
  }
  if (t < 64) { marr[t] = -INFINITY; larr[t] = 0.f; }
  float acc[16] = {};
  int ntiles = bi + 1;
  for (int jt = 0; jt < ntiles; jt++) {
    __syncthreads();
#pragma unroll
    for (int i = 0; i < 4; i++) {  // load K,V tiles
      int lin = i * 256 + t;
      int row = lin >> 4, col = (lin & 15) * 4;
      size_t goff = ((size_t)(b * NN) + jt * 64 + row) * DD + h * DHH + col;
      *(float4*)&ks[row][col] = *(const float4*)(k + goff);
      *(float4*)&vs[row][col] = *(const float4*)(v + goff);
    }
    __syncthreads();
    {  // phase1: scores row r, cols w*16..+15
      float s[16] = {};
#pragma unroll
      for (int d4 = 0; d4 < 64; d4 += 4) {
#pragma unroll
        for (int j = 0; j < 16; j++) {
          float4 k4 = *(const float4*)&ks[w * 16 + j][d4];
          s[j] += qreg[d4] * k4.x + qreg[d4 + 1] * k4.y +
                  qreg[d4 + 2] * k4.z + qreg[d4 + 3] * k4.w;
        }
      }
#pragma unroll
      for (int j = 0; j < 16; j++) sc[r][w * 16 + j] = s[j];
    }
    __syncthreads();
    {  // online softmax: wave w owns rows w*16..+15
      int lane = t & 63;
      for (int rr = w * 16; rr < w * 16 + 16; rr++) {
        int ig = i0 + rr;
        int jg = jt * 64 + lane;
        float s = sc[rr][lane];
        if (jg > ig) s = -INFINITY;
        float m_old = marr[rr];
        float tm = s;
#pragma unroll
        for (int m = 32; m; m >>= 1) tm = fmaxf(tm, __shfl_xor(tm, m, 64));
        float m_new = fmaxf(m_old, tm);
        float p = __expf(s - m_new);
        float ts = p;
#pragma unroll
        for (int m = 32; m; m >>= 1) ts += __shfl_xor(ts, m, 64);
        float alpha = __expf(m_old - m_new);
        sc[rr][lane] = p;
        if (lane == 0) {
          marr[rr] = m_new; larr[rr] = larr[rr] * alpha + ts; aarr[rr] = alpha;
        }
      }
    }
    __syncthreads();
    {  // phase2: acc[r][w*16..+15] += P @ V
      float al = aarr[r];
#pragma unroll
      for (int dd = 0; dd < 16; dd++) acc[dd] *= al;
      for (int j = 0; j < 64; j++) {
        float p = sc[r][j];
        const float* vrow = &vs[j][w * 16];
#pragma unroll
        for (int dd = 0; dd < 16; dd += 4) {
          float4 v4 = *(const float4*)(vrow + dd);
          acc[dd] += p * v4.x; acc[dd + 1] += p * v4.y;
          acc[dd + 2] += p * v4.z; acc[dd + 3] += p * v4.w;
        }
      }
    }
  }
  if (knn) {
    __syncthreads();
    {  // memory logits (already scaled in topk kernel)
      int lane = t & 63;
      size_t rowbase = ((size_t)b * HH + h) * NN + i0;
      for (int rr = w * 16; rr < w * 16 + 16; rr++) {
        float s = (lane < TOPKK) ? topv[(rowbase + rr) * TOPKK + lane] : -INFINITY;
        float m_old = marr[rr];
        float tm = s;
#pragma unroll
        for (int m = 32; m; m >>= 1) tm = fmaxf(tm, __shfl_xor(tm, m, 64));
        float m_new = fmaxf(m_old, tm);
        float p = __expf(s - m_new);
        float ts = p;
#pragma unroll
        for (int m = 32; m; m >>= 1) ts += __shfl_xor(ts, m, 64);
        float alpha = __expf(m_old - m_new);
        sc[rr][lane] = p;
        if (lane < TOPKK) pidx[rr][lane] = topi[(rowbase + rr) * TOPKK + lane];
        if (lane == 0) {
          marr[rr] = m_new; larr[rr] = larr[rr] * alpha + ts; aarr[rr] = alpha;
        }
      }
    }
    __syncthreads();
    {
      float al = aarr[r];
#pragma unroll
      for (int dd = 0; dd < 16; dd++) acc[dd] *= al;
      const float* mvb = mem_v + (size_t)b * MEMM * DHH;
      for (int kk = 0; kk < TOPKK; kk++) {
        float p = sc[r][kk];
        const float* mrow = mvb + (size_t)pidx[r][kk] * DHH + w * 16;
#pragma unroll
        for (int dd = 0; dd < 16; dd += 4) {
          float4 m4 = *(const float4*)(mrow + dd);
          acc[dd] += p * m4.x; acc[dd + 1] += p * m4.y;
          acc[dd + 2] += p * m4.z; acc[dd + 3] += p * m4.w;
        }
      }
    }
  }
  {  // epilogue: out = acc / l
    float linv = 1.0f / larr[r];
    float* aop = ao + ((size_t)(b * NN) + iglob) * DD + h * DHH + w * 16;
#pragma unroll
    for (int dd = 0; dd < 16; dd += 4) {
      float4 o;
      o.x = acc[dd] * linv; o.y = acc[dd + 1] * linv;
      o.z = acc[dd + 2] * linv; o.w = acc[dd + 3] * linv;
      *(float4*)(aop + dd) = o;
    }
  }
}

// ---------------- host ----------------
extern "C" void kernel_launch(void* const* d_in, const int* in_sizes, int n_in,
                              void* d_out, int out_size, void* d_ws, size_t ws_size,
                              hipStream_t stream) {
  const float* x_in  = (const float*)d_in[0];
  const float* Wq    = (const float*)d_in[1];
  const float* Wk    = (const float*)d_in[2];
  const float* Wv    = (const float*)d_in[3];
  const float* Wo    = (const float*)d_in[4];
  const float* ln1_s = (const float*)d_in[5];
  const float* ln1_b = (const float*)d_in[6];
  const float* ln2_s = (const float*)d_in[7];
  const float* ln2_b = (const float*)d_in[8];
  const float* W1    = (const float*)d_in[9];
  const float* W2    = (const float*)d_in[10];
  const float* lnf_s = (const float*)d_in[11];
  const float* lnf_b = (const float*)d_in[12];
  const float* mem_k = (const float*)d_in[13];
  const float* mem_v = (const float*)d_in[14];

  // workspace layout (floats), total 14,680,064 floats = 58.72 MB:
  //  xb   [0        .. 2097152)   8 MB   residual stream
  //  hb   [2097152  .. 4194304)   8 MB   LN output
  //  qb   [4194304  .. 6291456)   8 MB \
  //  kb   [6291456  .. 8388608)   8 MB  | ffb (32 MB, NT*FF) aliases these
  //  vb   [8388608  .. 10485760)  8 MB  | four (dead during FFN)
  //  aob  [10485760 .. 12582912)  8 MB /
  //  tvb  [12582912 .. 13631488)  4 MB   top-k values  (B*H*N*TOPK = 1M elems)
  //  tib  [13631488 .. 14680064)  4 MB   top-k indices (1M elems)
  float* ws  = (float*)d_ws;
  float* xb  = ws;
  float* hb  = ws + 2097152;
  float* qb  = ws + 4194304;
  float* kb  = ws + 6291456;
  float* vb  = ws + 8388608;
  float* aob = ws + 10485760;
  float* ffb = ws + 4194304;           // aliases qb..aob
  float* tvb = ws + 12582912;
  int*   tib = (int*)(ws + 13631488);

  dim3 blk(256);
  const size_t DD2 = (size_t)DD * DD;
  for (int l = 0; l < DEPTHH; l++) {
    const float* xcur = (l == 0) ? x_in : xb;
    ln_kernel<<<NT, blk, 0, stream>>>(xcur, ln1_s + l * DD, ln1_b + l * DD, hb);
    gemm_kernel<0><<<dim3(8, 64), blk, 0, stream>>>(hb, Wq + l * DD2, nullptr, qb, NT, DD, DD);
    gemm_kernel<0><<<dim3(8, 64), blk, 0, stream>>>(hb, Wk + l * DD2, nullptr, kb, NT, DD, DD);
    gemm_kernel<0><<<dim3(8, 64), blk, 0, stream>>>(hb, Wv + l * DD2, nullptr, vb, NT, DD, DD);
    int mi = (l == 3) ? 0 : ((l == 4) ? 1 : -1);
    if (mi >= 0)
      knn_topk_kernel<<<dim3(16, 8, 8), blk, 0, stream>>>(
          qb, mem_k + (size_t)mi * BB * MEMM * DHH, tvb, tib);
    attn_kernel<<<dim3(8, 8, 8), blk, 0, stream>>>(
        qb, kb, vb, aob, tvb, tib,
        mem_v + (size_t)(mi < 0 ? 0 : mi) * BB * MEMM * DHH, mi >= 0 ? 1 : 0);
    gemm_kernel<2><<<dim3(8, 64), blk, 0, stream>>>(aob, Wo + l * DD2, xcur, xb, NT, DD, DD);
    ln_kernel<<<NT, blk, 0, stream>>>(xb, ln2_s + l * DD, ln2_b + l * DD, hb);
    gemm_kernel<1><<<dim3(32, 64), blk, 0, stream>>>(
        hb, W1 + (size_t)l * DD * FFF, nullptr, ffb, NT, FFF, DD);
    gemm_kernel<2><<<dim3(8, 64), blk, 0, stream>>>(
        ffb, W2 + (size_t)l * FFF * DD, xb, xb, NT, DD, FFF);
  }
  ln_kernel<<<NT, blk, 0, stream>>>(xb, lnf_s, lnf_b, (float*)d_out);
}